// Round 1
// baseline (253.835 us; speedup 1.0000x reference)
//
#include <hip/hip_runtime.h>
#include <math.h>

#define NHEADS 4
#define HDIM   32
#define DMODEL 128
#define SLEN   8192
#define BATCH  8
#define QKVC   384   // 3 * NHEADS * HDIM

// ---------------------------------------------------------------------------
// Kernel 1: fused QKV projection + per-position head-mixing attention.
// One block = 32 consecutive positions (flattened over B*S).
//   Phase 1: qkv tile (32 x 384) = x tile (32 x 128) @ W_qkv (128 x 384) + b
//   Phase 2: per position p: scores[qh][kh] = q.k/sqrt(32); softmax over kh;
//            out[qh][d] = sum_kh attn*v  -> attn_out[pos][qh*32+d]  (f32, ws)
// ---------------------------------------------------------------------------
__global__ __launch_bounds__(256, 2) void k_qkv_attn(
    const float* __restrict__ x,
    const float* __restrict__ Wqkv,
    const float* __restrict__ bqkv,
    float* __restrict__ attn_out)
{
    __shared__ float xs[32][DMODEL];
    __shared__ float qs[32][QKVC + 1];   // +1 pad: breaks 384-stride bank alias

    const int tid = threadIdx.x;
    const long p0 = (long)blockIdx.x * 32;   // global position base in [0, B*S)

    // stage x tile: 32*128 floats = 1024 float4, 4 per thread, coalesced
    {
        const float4* src = (const float4*)(x + p0 * DMODEL);
        float4* dst = (float4*)(&xs[0][0]);
        #pragma unroll
        for (int i = 0; i < 4; ++i) dst[tid + i * 256] = src[tid + i * 256];
    }
    __syncthreads();

    // QKV GEMM: thread (cx = tid&63, py = tid>>6) computes
    //   cols c = cx + 64*j (j<6), rows p = py*8 + i (i<8)
    const int cx = tid & 63;
    const int py = tid >> 6;
    float acc[8][6];
    #pragma unroll
    for (int i = 0; i < 8; ++i)
        #pragma unroll
        for (int j = 0; j < 6; ++j) acc[i][j] = 0.f;

    for (int k = 0; k < DMODEL; ++k) {
        float wv[6];
        #pragma unroll
        for (int j = 0; j < 6; ++j) wv[j] = Wqkv[k * QKVC + cx + 64 * j];
        #pragma unroll
        for (int i = 0; i < 8; ++i) {
            const float xv = xs[py * 8 + i][k];
            #pragma unroll
            for (int j = 0; j < 6; ++j) acc[i][j] += xv * wv[j];
        }
    }
    #pragma unroll
    for (int j = 0; j < 6; ++j) {
        const float bb = bqkv[cx + 64 * j];
        #pragma unroll
        for (int i = 0; i < 8; ++i)
            qs[py * 8 + i][cx + 64 * j] = acc[i][j] + bb;
    }
    __syncthreads();

    // attention: 128 threads, one per (p = tid>>2, qh = tid&3)
    if (tid < 128) {
        const int p  = tid >> 2;
        const int qh = tid & 3;
        const float* row = &qs[p][0];
        const float scale = 0.17677669529663687f;   // 32^-0.5

        float q[HDIM];
        #pragma unroll
        for (int d = 0; d < HDIM; ++d) q[d] = row[qh * 96 + d];

        float sc[NHEADS];
        #pragma unroll
        for (int kh = 0; kh < NHEADS; ++kh) {
            float s = 0.f;
            #pragma unroll
            for (int d = 0; d < HDIM; ++d) s += q[d] * row[kh * 96 + 32 + d];
            sc[kh] = s * scale;
        }
        const float m = fmaxf(fmaxf(sc[0], sc[1]), fmaxf(sc[2], sc[3]));
        float e[NHEADS], sum = 0.f;
        #pragma unroll
        for (int kh = 0; kh < NHEADS; ++kh) { e[kh] = expf(sc[kh] - m); sum += e[kh]; }
        const float inv = 1.f / sum;

        float o[HDIM];
        #pragma unroll
        for (int d = 0; d < HDIM; ++d) o[d] = 0.f;
        #pragma unroll
        for (int kh = 0; kh < NHEADS; ++kh) {
            const float w = e[kh] * inv;
            #pragma unroll
            for (int d = 0; d < HDIM; ++d) o[d] += w * row[kh * 96 + 64 + d];
        }

        float4* dst = (float4*)(attn_out + (p0 + p) * DMODEL + qh * HDIM);
        #pragma unroll
        for (int i = 0; i < 8; ++i) dst[i] = ((const float4*)o)[i];
    }
}

// ---------------------------------------------------------------------------
// Kernel 2: init output with bias (also clears the 0xAA poison).
// out[b, r, j] = b_out[j];  8*128*128 = 131072 elements
// ---------------------------------------------------------------------------
__global__ void k_init_out(float* __restrict__ out, const float* __restrict__ bout)
{
    const int idx = blockIdx.x * blockDim.x + threadIdx.x;
    out[idx] = bout[idx & (DMODEL - 1)];
}

// ---------------------------------------------------------------------------
// Kernel 3: final batched GEMM with split-K + atomic accumulation.
//   out[b] (128x128) += reshape(attn_out[b], 128x8192) @ W_out(8192x128)
//   A_b[r][c] = attn_out[b][r*64 + c/128][c%128]
// Grid: (b, kc) = 8 * 32 blocks; K-chunk = 256 (two 128-sub-chunks).
// ---------------------------------------------------------------------------
__global__ __launch_bounds__(256, 1) void k_final_gemm(
    const float* __restrict__ attn_out,
    const float* __restrict__ Wout,
    float* __restrict__ out)
{
    __shared__ float As[128][129];   // +1 pad: column reads conflict-free
    __shared__ float Ws[128][128];

    const int tid = threadIdx.x;
    const int b  = blockIdx.x >> 5;
    const int kc = blockIdx.x & 31;
    const int tx = tid & 15;
    const int ty = tid >> 4;

    const float* Ab = attn_out + (long)b * SLEN * DMODEL;

    float acc[8][8];
    #pragma unroll
    for (int i = 0; i < 8; ++i)
        #pragma unroll
        for (int j = 0; j < 8; ++j) acc[i][j] = 0.f;

    for (int h = 0; h < 2; ++h) {
        __syncthreads();   // protect LDS from previous sub-chunk's readers
        // stage A: As[r][f] = Ab[(r*64 + kc*2 + h)*128 + f]   (coalesced f4 loads)
        #pragma unroll
        for (int i = 0; i < 16; ++i) {
            const int idx = tid + i * 256;        // 0..4095 float4 units
            const int r  = idx >> 5;
            const int f4 = idx & 31;
            const float4 v = *(const float4*)(Ab + ((long)((r << 6) + kc * 2 + h) << 7) + (f4 << 2));
            As[r][f4 * 4 + 0] = v.x;
            As[r][f4 * 4 + 1] = v.y;
            As[r][f4 * 4 + 2] = v.z;
            As[r][f4 * 4 + 3] = v.w;
        }
        // stage W: rows kc*256 + h*128 .. +128 of W_out, contiguous
        {
            const float* Wsrc = Wout + (long)((kc * 2 + h) * 128) * 128;
            #pragma unroll
            for (int i = 0; i < 16; ++i) {
                const int idx = tid + i * 256;
                *(((float4*)&Ws[0][0]) + idx) = *(((const float4*)Wsrc) + idx);
            }
        }
        __syncthreads();

        // compute: 8x8 register tile per thread
        for (int k = 0; k < 128; ++k) {
            float a[8];
            #pragma unroll
            for (int i = 0; i < 8; ++i) a[i] = As[ty * 8 + i][k];
            const float4 w0 = *(const float4*)(&Ws[k][tx * 8]);
            const float4 w1 = *(const float4*)(&Ws[k][tx * 8 + 4]);
            const float w[8] = { w0.x, w0.y, w0.z, w0.w, w1.x, w1.y, w1.z, w1.w };
            #pragma unroll
            for (int i = 0; i < 8; ++i)
                #pragma unroll
                for (int j = 0; j < 8; ++j)
                    acc[i][j] += a[i] * w[j];
        }
    }

    float* Cb = out + (long)b * DMODEL * DMODEL;
    #pragma unroll
    for (int i = 0; i < 8; ++i)
        #pragma unroll
        for (int j = 0; j < 8; ++j)
            atomicAdd(&Cb[(ty * 8 + i) * DMODEL + tx * 8 + j], acc[i][j]);
}

// ---------------------------------------------------------------------------
extern "C" void kernel_launch(void* const* d_in, const int* in_sizes, int n_in,
                              void* d_out, int out_size, void* d_ws, size_t ws_size,
                              hipStream_t stream)
{
    const float* x    = (const float*)d_in[0];
    const float* Wqkv = (const float*)d_in[1];
    const float* bqkv = (const float*)d_in[2];
    const float* Wout = (const float*)d_in[3];
    const float* bout = (const float*)d_in[4];
    float* out  = (float*)d_out;
    float* attn = (float*)d_ws;    // B*S*128 f32 = 32 MiB scratch

    const int nPos = BATCH * SLEN;                 // 65536
    k_qkv_attn<<<nPos / 32, 256, 0, stream>>>(x, Wqkv, bqkv, attn);
    k_init_out<<<(BATCH * DMODEL * DMODEL) / 256, 256, 0, stream>>>(out, bout);
    k_final_gemm<<<BATCH * 32, 256, 0, stream>>>(attn, Wout, out);
}

// Round 2
// 118.070 us; speedup vs baseline: 2.1499x; 2.1499x over previous
//
#include <hip/hip_runtime.h>
#include <math.h>

#define NHEADS 4
#define HDIM   32
#define DMODEL 128
#define SLEN   8192
#define BATCH  8
#define QKVC   384   // 3 * NHEADS * HDIM

typedef __bf16 bf16x8 __attribute__((ext_vector_type(8)));
typedef float  f32x4  __attribute__((ext_vector_type(4)));

// round-to-nearest-even f32 -> bf16 bits
static __device__ __forceinline__ unsigned short f2bf(float f) {
    union { float f; unsigned int u; } v; v.f = f;
    unsigned int r = (v.u + 0x7FFFu + ((v.u >> 16) & 1u)) >> 16;
    return (unsigned short)r;
}

// ---------------------------------------------------------------------------
// Kernel 0: convert + transpose W_out (f32 [8192][128]) -> Wt bf16 [128][8192]
// 64 blocks, each handles 128 k-rows.
// ---------------------------------------------------------------------------
__global__ __launch_bounds__(256) void k_conv_wout(
    const float* __restrict__ Wout, unsigned short* __restrict__ Wt)
{
    __shared__ unsigned short ts[128][136];   // [n][kk], padded
    const int tid = threadIdx.x;
    const int kb  = blockIdx.x;               // k-row block
    const float* src = Wout + (long)kb * 128 * 128;

    #pragma unroll
    for (int i = 0; i < 64; ++i) {
        const int idx = tid + i * 256;        // 0..16383
        const int kk = idx >> 7, n = idx & 127;
        ts[n][kk] = f2bf(src[idx]);
    }
    __syncthreads();
    #pragma unroll
    for (int i = 0; i < 64; ++i) {
        const int idx = tid + i * 256;
        const int n = idx >> 7, kk = idx & 127;
        Wt[(long)n * SLEN + kb * 128 + kk] = ts[n][kk];
    }
}

// ---------------------------------------------------------------------------
// Kernel 1: fused QKV projection + per-position head-mixing attention.
// (unchanged fp32 GEMM; epilogue now stores attn_out as bf16)
// ---------------------------------------------------------------------------
__global__ __launch_bounds__(256, 2) void k_qkv_attn(
    const float* __restrict__ x,
    const float* __restrict__ Wqkv,
    const float* __restrict__ bqkv,
    unsigned short* __restrict__ attn_out)   // bf16 [65536][128]
{
    __shared__ float xs[32][DMODEL];
    __shared__ float qs[32][QKVC + 1];

    const int tid = threadIdx.x;
    const long p0 = (long)blockIdx.x * 32;

    {
        const float4* src = (const float4*)(x + p0 * DMODEL);
        float4* dst = (float4*)(&xs[0][0]);
        #pragma unroll
        for (int i = 0; i < 4; ++i) dst[tid + i * 256] = src[tid + i * 256];
    }
    __syncthreads();

    const int cx = tid & 63;
    const int py = tid >> 6;
    float acc[8][6];
    #pragma unroll
    for (int i = 0; i < 8; ++i)
        #pragma unroll
        for (int j = 0; j < 6; ++j) acc[i][j] = 0.f;

    for (int k = 0; k < DMODEL; ++k) {
        float wv[6];
        #pragma unroll
        for (int j = 0; j < 6; ++j) wv[j] = Wqkv[k * QKVC + cx + 64 * j];
        #pragma unroll
        for (int i = 0; i < 8; ++i) {
            const float xv = xs[py * 8 + i][k];
            #pragma unroll
            for (int j = 0; j < 6; ++j) acc[i][j] += xv * wv[j];
        }
    }
    #pragma unroll
    for (int j = 0; j < 6; ++j) {
        const float bb = bqkv[cx + 64 * j];
        #pragma unroll
        for (int i = 0; i < 8; ++i)
            qs[py * 8 + i][cx + 64 * j] = acc[i][j] + bb;
    }
    __syncthreads();

    if (tid < 128) {
        const int p  = tid >> 2;
        const int qh = tid & 3;
        const float* row = &qs[p][0];
        const float scale = 0.17677669529663687f;

        float q[HDIM];
        #pragma unroll
        for (int d = 0; d < HDIM; ++d) q[d] = row[qh * 96 + d];

        float sc[NHEADS];
        #pragma unroll
        for (int kh = 0; kh < NHEADS; ++kh) {
            float s = 0.f;
            #pragma unroll
            for (int d = 0; d < HDIM; ++d) s += q[d] * row[kh * 96 + 32 + d];
            sc[kh] = s * scale;
        }
        const float m = fmaxf(fmaxf(sc[0], sc[1]), fmaxf(sc[2], sc[3]));
        float e[NHEADS], sum = 0.f;
        #pragma unroll
        for (int kh = 0; kh < NHEADS; ++kh) { e[kh] = expf(sc[kh] - m); sum += e[kh]; }
        const float inv = 1.f / sum;

        float o[HDIM];
        #pragma unroll
        for (int d = 0; d < HDIM; ++d) o[d] = 0.f;
        #pragma unroll
        for (int kh = 0; kh < NHEADS; ++kh) {
            const float w = e[kh] * inv;
            #pragma unroll
            for (int d = 0; d < HDIM; ++d) o[d] += w * row[kh * 96 + 64 + d];
        }

        unsigned short o16[HDIM];
        #pragma unroll
        for (int d = 0; d < HDIM; ++d) o16[d] = f2bf(o[d]);
        uint4* dst = (uint4*)(attn_out + (p0 + p) * DMODEL + qh * HDIM);
        #pragma unroll
        for (int i = 0; i < 4; ++i) dst[i] = ((const uint4*)o16)[i];
    }
}

// ---------------------------------------------------------------------------
// Kernel 2: final GEMM partials via bf16 MFMA.
//   C(1024x128) = Aflat(1024x8192 bf16) @ W(8192x128)   [A = attn buffer!]
// Grid: 16 M-tiles (64 rows) x 16 K-chunks (512) = 256 blocks, 256 thr.
// Each block: 4 stages of 128 k; per stage: LDS {A 64x128, Wt 128x128} bf16;
// wave w owns n-tiles {2w,2w+1}; acc f32x4[4][2]. Partials -> ws (f32).
// ---------------------------------------------------------------------------
__global__ __launch_bounds__(256, 2) void k_fgemm_mfma(
    const unsigned short* __restrict__ attnBf,   // [1024][8192] bf16 (flat view)
    const unsigned short* __restrict__ WtBf,     // [128][8192] bf16
    float* __restrict__ P)                       // [16][1024][128] f32 partials
{
    __shared__ unsigned short As[64][136];
    __shared__ unsigned short Ws[128][136];

    const int tid   = threadIdx.x;
    const int mtile = blockIdx.x >> 4;     // 0..15
    const int kc    = blockIdx.x & 15;     // 0..15
    const int lane  = tid & 63;
    const int wave  = tid >> 6;            // 0..3
    const int l16   = lane & 15;
    const int lhi   = lane >> 4;           // 0..3

    f32x4 acc[4][2];
    #pragma unroll
    for (int mf = 0; mf < 4; ++mf)
        #pragma unroll
        for (int nt = 0; nt < 2; ++nt) acc[mf][nt] = (f32x4){0.f, 0.f, 0.f, 0.f};

    for (int st = 0; st < 4; ++st) {
        const int k0 = kc * 512 + st * 128;
        __syncthreads();
        // stage A: 64 rows x 128 k  (1024 16B-chunks, 4/thread)
        #pragma unroll
        for (int i = 0; i < 4; ++i) {
            const int c = tid + i * 256;
            const int m = c >> 4, k8 = c & 15;
            const uint4 v = *(const uint4*)(attnBf + (long)(mtile * 64 + m) * SLEN + k0 + k8 * 8);
            *(uint4*)(&As[m][k8 * 8]) = v;
        }
        // stage Wt: 128 n-rows x 128 k  (2048 16B-chunks, 8/thread)
        #pragma unroll
        for (int i = 0; i < 8; ++i) {
            const int c = tid + i * 256;
            const int n = c >> 4, k8 = c & 15;
            const uint4 v = *(const uint4*)(WtBf + (long)n * SLEN + k0 + k8 * 8);
            *(uint4*)(&Ws[n][k8 * 8]) = v;
        }
        __syncthreads();

        #pragma unroll
        for (int ks = 0; ks < 4; ++ks) {
            const int kk = ks * 32 + lhi * 8;
            bf16x8 af[4], bf[2];
            #pragma unroll
            for (int mf = 0; mf < 4; ++mf)
                af[mf] = __builtin_bit_cast(bf16x8, *(const uint4*)(&As[mf * 16 + l16][kk]));
            #pragma unroll
            for (int nt = 0; nt < 2; ++nt)
                bf[nt] = __builtin_bit_cast(bf16x8, *(const uint4*)(&Ws[(wave * 2 + nt) * 16 + l16][kk]));
            #pragma unroll
            for (int mf = 0; mf < 4; ++mf)
                #pragma unroll
                for (int nt = 0; nt < 2; ++nt)
                    acc[mf][nt] = __builtin_amdgcn_mfma_f32_16x16x32_bf16(af[mf], bf[nt], acc[mf][nt], 0, 0, 0);
        }
    }

    // write partials: P[kc][mtile*64 + m][n]
    float* Pp = P + ((long)kc * 1024 + mtile * 64) * 128;
    #pragma unroll
    for (int mf = 0; mf < 4; ++mf) {
        #pragma unroll
        for (int nt = 0; nt < 2; ++nt) {
            const int n = (wave * 2 + nt) * 16 + l16;
            #pragma unroll
            for (int r = 0; r < 4; ++r) {
                const int m = mf * 16 + lhi * 4 + r;
                Pp[m * 128 + n] = acc[mf][nt][r];
            }
        }
    }
}

// ---------------------------------------------------------------------------
// Kernel 3: reduce 16 K-chunk partials + bias -> out (also clears poison).
// ---------------------------------------------------------------------------
__global__ __launch_bounds__(256) void k_reduce(
    const float* __restrict__ P, const float* __restrict__ bout,
    float* __restrict__ out)
{
    const int idx = blockIdx.x * 256 + threadIdx.x;   // 0..131071
    float v = bout[idx & 127];
    #pragma unroll
    for (int kcc = 0; kcc < 16; ++kcc) v += P[(long)kcc * 131072 + idx];
    out[idx] = v;
}

// ---------------------------------------------------------------------------
extern "C" void kernel_launch(void* const* d_in, const int* in_sizes, int n_in,
                              void* d_out, int out_size, void* d_ws, size_t ws_size,
                              hipStream_t stream)
{
    const float* x    = (const float*)d_in[0];
    const float* Wqkv = (const float*)d_in[1];
    const float* bqkv = (const float*)d_in[2];
    const float* Wout = (const float*)d_in[3];
    const float* bout = (const float*)d_in[4];
    float* out = (float*)d_out;

    // ws layout: [0,16MB) attn bf16 | [16,18MB) Wt bf16 | [18,26MB) partials f32
    unsigned short* attnBf = (unsigned short*)d_ws;
    unsigned short* WtBf   = (unsigned short*)((char*)d_ws + (16u << 20));
    float*          P      = (float*)((char*)d_ws + (18u << 20));

    k_conv_wout<<<64, 256, 0, stream>>>(Wout, WtBf);
    k_qkv_attn<<<(BATCH * SLEN) / 32, 256, 0, stream>>>(x, Wqkv, bqkv, attnBf);
    k_fgemm_mfma<<<256, 256, 0, stream>>>(attnBf, WtBf, P);
    k_reduce<<<(BATCH * DMODEL * DMODEL) / 256, 256, 0, stream>>>(P, bout, out);
}

// Round 3
// 50.634 us; speedup vs baseline: 5.0132x; 2.3318x over previous
//
#include <hip/hip_runtime.h>
#include <math.h>

#define NHEADS 4
#define HDIM   32
#define DMODEL 128
#define SLEN   8192
#define BATCH  8
#define QKVC   384   // 3 * NHEADS * HDIM

typedef __bf16 bf16x8 __attribute__((ext_vector_type(8)));
typedef float  f32x4  __attribute__((ext_vector_type(4)));

// round-to-nearest-even f32 -> bf16 bits
static __device__ __forceinline__ unsigned short f2bf(float f) {
    union { float f; unsigned int u; } v; v.f = f;
    unsigned int r = (v.u + 0x7FFFu + ((v.u >> 16) & 1u)) >> 16;
    return (unsigned short)r;
}

// ---------------------------------------------------------------------------
// Kernel 0: convert + transpose W_out (f32 [8192][128]) -> Wt bf16 [128][8192]
// ---------------------------------------------------------------------------
__global__ __launch_bounds__(256) void k_conv_wout(
    const float* __restrict__ Wout, unsigned short* __restrict__ Wt)
{
    __shared__ unsigned short ts[128][136];
    const int tid = threadIdx.x;
    const int kb  = blockIdx.x;
    const float* src = Wout + (long)kb * 128 * 128;

    #pragma unroll
    for (int i = 0; i < 64; ++i) {
        const int idx = tid + i * 256;
        const int kk = idx >> 7, n = idx & 127;
        ts[n][kk] = f2bf(src[idx]);
    }
    __syncthreads();
    #pragma unroll
    for (int i = 0; i < 64; ++i) {
        const int idx = tid + i * 256;
        const int n = idx >> 7, kk = idx & 127;
        Wt[(long)n * SLEN + kb * 128 + kk] = ts[n][kk];
    }
}

// ---------------------------------------------------------------------------
// Kernel 1: fused QKV projection (bf16 MFMA, W_qkv fragments in registers)
//           + per-position head-mixing attention.
// Grid 512 blocks x 256 thr; each block: 4 iters of 32 positions.
// Per iter: stage x tile bf16 in LDS -> MFMA (2 m-frags x 6 n-frags/wave x
// 4 k-slices) -> write qkv^T f32 to LDS -> 128-thread softmax epilogue ->
// coalesced bf16 store via LDS.
// ---------------------------------------------------------------------------
__global__ __launch_bounds__(256, 2) void k_qkv_attn_mfma(
    const float* __restrict__ x,
    const float* __restrict__ Wqkv,
    const float* __restrict__ bqkv,
    unsigned short* __restrict__ attn_out)   // bf16 [65536][128]
{
    __shared__ unsigned short xs[32][136];   // x tile bf16 (reused for output)
    __shared__ float qsT[QKVC][33];          // qkv transposed: [channel][pos]

    const int tid  = threadIdx.x;
    const int lane = tid & 63;
    const int wave = tid >> 6;
    const int l16  = lane & 15;
    const int lhi  = lane >> 4;

    // --- one-time: wave's W_qkv B-fragments (n-tiles 6w..6w+5) in registers
    bf16x8 wf[6][4];
    #pragma unroll
    for (int j = 0; j < 6; ++j) {
        const int n = wave * 96 + j * 16 + l16;
        #pragma unroll
        for (int ks = 0; ks < 4; ++ks) {
            unsigned short t[8];
            #pragma unroll
            for (int e = 0; e < 8; ++e)
                t[e] = f2bf(Wqkv[(ks * 32 + lhi * 8 + e) * QKVC + n]);
            wf[j][ks] = __builtin_bit_cast(bf16x8, *(const uint4*)t);
        }
    }
    float bq[6];
    #pragma unroll
    for (int j = 0; j < 6; ++j) bq[j] = bqkv[wave * 96 + j * 16 + l16];

    for (int it = 0; it < 4; ++it) {
        const long p0 = ((long)blockIdx.x * 4 + it) * 32;

        __syncthreads();   // prev iter fully done with xs/qsT
        // stage x tile f32 -> bf16 (coalesced float4 reads)
        #pragma unroll
        for (int i = 0; i < 4; ++i) {
            const int idx = tid + i * 256;        // 0..1023
            const int r = idx >> 5, k4 = idx & 31;
            const float4 v = *(const float4*)(x + (p0 + r) * DMODEL + k4 * 4);
            unsigned short t[4] = { f2bf(v.x), f2bf(v.y), f2bf(v.z), f2bf(v.w) };
            *(unsigned long long*)(&xs[r][k4 * 4]) = *(const unsigned long long*)t;
        }
        __syncthreads();

        // MFMA: qkv[32 x 384] for this tile
        f32x4 acc[2][6];
        #pragma unroll
        for (int mf = 0; mf < 2; ++mf)
            #pragma unroll
            for (int j = 0; j < 6; ++j) acc[mf][j] = (f32x4){0.f, 0.f, 0.f, 0.f};

        #pragma unroll
        for (int ks = 0; ks < 4; ++ks) {
            bf16x8 af[2];
            af[0] = __builtin_bit_cast(bf16x8, *(const uint4*)(&xs[l16][ks * 32 + lhi * 8]));
            af[1] = __builtin_bit_cast(bf16x8, *(const uint4*)(&xs[16 + l16][ks * 32 + lhi * 8]));
            #pragma unroll
            for (int mf = 0; mf < 2; ++mf)
                #pragma unroll
                for (int j = 0; j < 6; ++j)
                    acc[mf][j] = __builtin_amdgcn_mfma_f32_16x16x32_bf16(af[mf], wf[j][ks], acc[mf][j], 0, 0, 0);
        }

        // write qkv^T (+bias) to LDS
        #pragma unroll
        for (int mf = 0; mf < 2; ++mf)
            #pragma unroll
            for (int j = 0; j < 6; ++j) {
                const int n = wave * 96 + j * 16 + l16;
                #pragma unroll
                for (int r = 0; r < 4; ++r)
                    qsT[n][mf * 16 + lhi * 4 + r] = acc[mf][j][r] + bq[j];
            }
        __syncthreads();

        // attention epilogue: thread (p = tid&31, qh = tid>>5), tid < 128.
        // Lane-consecutive p => conflict-free LDS; qh halves broadcast.
        if (tid < 128) {
            const int p  = tid & 31;
            const int qh = tid >> 5;
            const float scale = 0.17677669529663687f;   // 32^-0.5

            float q[HDIM];
            #pragma unroll
            for (int d = 0; d < HDIM; ++d) q[d] = qsT[qh * 96 + d][p];

            float sc[NHEADS];
            #pragma unroll
            for (int kh = 0; kh < NHEADS; ++kh) {
                float s = 0.f;
                #pragma unroll
                for (int d = 0; d < HDIM; ++d) s += q[d] * qsT[kh * 96 + 32 + d][p];
                sc[kh] = s * scale;
            }
            const float m = fmaxf(fmaxf(sc[0], sc[1]), fmaxf(sc[2], sc[3]));
            float e[NHEADS], sum = 0.f;
            #pragma unroll
            for (int kh = 0; kh < NHEADS; ++kh) { e[kh] = __expf(sc[kh] - m); sum += e[kh]; }
            const float inv = 1.f / sum;

            float o[HDIM];
            #pragma unroll
            for (int d = 0; d < HDIM; ++d) o[d] = 0.f;
            #pragma unroll
            for (int kh = 0; kh < NHEADS; ++kh) {
                const float w = e[kh] * inv;
                #pragma unroll
                for (int d = 0; d < HDIM; ++d) o[d] += w * qsT[kh * 96 + 64 + d][p];
            }

            // pack bf16 into xs[p][qh*32 + d] (xs tile is dead now)
            #pragma unroll
            for (int d = 0; d < HDIM; d += 2) {
                unsigned int pk = (unsigned int)f2bf(o[d]) | ((unsigned int)f2bf(o[d + 1]) << 16);
                *(unsigned int*)(&xs[p][qh * 32 + d]) = pk;
            }
        }
        __syncthreads();

        // cooperative coalesced store: 32 rows x 128 bf16 = 512 uint4
        #pragma unroll
        for (int i = 0; i < 2; ++i) {
            const int idx = tid + i * 256;
            const int r = idx >> 4, c = idx & 15;
            *(uint4*)(attn_out + (p0 + r) * DMODEL + c * 8) = *(const uint4*)(&xs[r][c * 8]);
        }
    }
}

// ---------------------------------------------------------------------------
// Kernel 2: final GEMM partials via bf16 MFMA.
//   C(1024x128) = Aflat(1024x8192 bf16) @ W(8192x128)
// ---------------------------------------------------------------------------
__global__ __launch_bounds__(256, 2) void k_fgemm_mfma(
    const unsigned short* __restrict__ attnBf,   // [1024][8192] bf16 (flat view)
    const unsigned short* __restrict__ WtBf,     // [128][8192] bf16
    float* __restrict__ P)                       // [16][1024][128] f32 partials
{
    __shared__ unsigned short As[64][136];
    __shared__ unsigned short Ws[128][136];

    const int tid   = threadIdx.x;
    const int mtile = blockIdx.x >> 4;
    const int kc    = blockIdx.x & 15;
    const int lane  = tid & 63;
    const int wave  = tid >> 6;
    const int l16   = lane & 15;
    const int lhi   = lane >> 4;

    f32x4 acc[4][2];
    #pragma unroll
    for (int mf = 0; mf < 4; ++mf)
        #pragma unroll
        for (int nt = 0; nt < 2; ++nt) acc[mf][nt] = (f32x4){0.f, 0.f, 0.f, 0.f};

    for (int st = 0; st < 4; ++st) {
        const int k0 = kc * 512 + st * 128;
        __syncthreads();
        #pragma unroll
        for (int i = 0; i < 4; ++i) {
            const int c = tid + i * 256;
            const int m = c >> 4, k8 = c & 15;
            const uint4 v = *(const uint4*)(attnBf + (long)(mtile * 64 + m) * SLEN + k0 + k8 * 8);
            *(uint4*)(&As[m][k8 * 8]) = v;
        }
        #pragma unroll
        for (int i = 0; i < 8; ++i) {
            const int c = tid + i * 256;
            const int n = c >> 4, k8 = c & 15;
            const uint4 v = *(const uint4*)(WtBf + (long)n * SLEN + k0 + k8 * 8);
            *(uint4*)(&Ws[n][k8 * 8]) = v;
        }
        __syncthreads();

        #pragma unroll
        for (int ks = 0; ks < 4; ++ks) {
            const int kk = ks * 32 + lhi * 8;
            bf16x8 af[4], bfr[2];
            #pragma unroll
            for (int mf = 0; mf < 4; ++mf)
                af[mf] = __builtin_bit_cast(bf16x8, *(const uint4*)(&As[mf * 16 + l16][kk]));
            #pragma unroll
            for (int nt = 0; nt < 2; ++nt)
                bfr[nt] = __builtin_bit_cast(bf16x8, *(const uint4*)(&Ws[(wave * 2 + nt) * 16 + l16][kk]));
            #pragma unroll
            for (int mf = 0; mf < 4; ++mf)
                #pragma unroll
                for (int nt = 0; nt < 2; ++nt)
                    acc[mf][nt] = __builtin_amdgcn_mfma_f32_16x16x32_bf16(af[mf], bfr[nt], acc[mf][nt], 0, 0, 0);
        }
    }

    float* Pp = P + ((long)kc * 1024 + mtile * 64) * 128;
    #pragma unroll
    for (int mf = 0; mf < 4; ++mf) {
        #pragma unroll
        for (int nt = 0; nt < 2; ++nt) {
            const int n = (wave * 2 + nt) * 16 + l16;
            #pragma unroll
            for (int r = 0; r < 4; ++r) {
                const int m = mf * 16 + lhi * 4 + r;
                Pp[m * 128 + n] = acc[mf][nt][r];
            }
        }
    }
}

// ---------------------------------------------------------------------------
// Kernel 3: reduce 16 K-chunk partials + bias -> out (also clears poison).
// ---------------------------------------------------------------------------
__global__ __launch_bounds__(256) void k_reduce(
    const float* __restrict__ P, const float* __restrict__ bout,
    float* __restrict__ out)
{
    const int idx = blockIdx.x * 256 + threadIdx.x;
    float v = bout[idx & 127];
    #pragma unroll
    for (int kcc = 0; kcc < 16; ++kcc) v += P[(long)kcc * 131072 + idx];
    out[idx] = v;
}

// ---------------------------------------------------------------------------
extern "C" void kernel_launch(void* const* d_in, const int* in_sizes, int n_in,
                              void* d_out, int out_size, void* d_ws, size_t ws_size,
                              hipStream_t stream)
{
    const float* x    = (const float*)d_in[0];
    const float* Wqkv = (const float*)d_in[1];
    const float* bqkv = (const float*)d_in[2];
    const float* Wout = (const float*)d_in[3];
    const float* bout = (const float*)d_in[4];
    float* out = (float*)d_out;

    // ws layout: [0,16MB) attn bf16 | [16,18MB) Wt bf16 | [18,26MB) partials f32
    unsigned short* attnBf = (unsigned short*)d_ws;
    unsigned short* WtBf   = (unsigned short*)((char*)d_ws + (16u << 20));
    float*          P      = (float*)((char*)d_ws + (18u << 20));

    k_conv_wout<<<64, 256, 0, stream>>>(Wout, WtBf);
    k_qkv_attn_mfma<<<512, 256, 0, stream>>>(x, Wqkv, bqkv, attnBf);
    k_fgemm_mfma<<<256, 256, 0, stream>>>(attnBf, WtBf, P);
    k_reduce<<<(BATCH * DMODEL * DMODEL) / 256, 256, 0, stream>>>(P, bout, out);
}